// Round 5
// baseline (4031.197 us; speedup 1.0000x reference)
//
#include <hip/hip_runtime.h>
#include <hip/hip_bf16.h>

typedef unsigned short u16;
typedef unsigned int u32;
typedef unsigned long long u64;
typedef __attribute__((ext_vector_type(8))) short short8;
typedef __attribute__((ext_vector_type(4))) int i32x4;
typedef __attribute__((ext_vector_type(4))) float floatx4;

#define I_DIM 256
#define H_DIM 1024
#define B_DIM 64
#define T_DIM 256
#define C_DIM 60
#define NWG   128
#define UPW   8      // hidden units per WG
#define BSTR  68     // pacc row stride (dwords): 16B-aligned, 2-way read aliasing

// LDS layout (bytes)
#define LDS_W_OFF    0        // 2*40*4*16 frags * 16B = 81920
#define LDS_PACC_OFF 81920    // 128 rows * 68 dw * 4B = 34816
#define LDS_BIAS_OFF 116736   // 32*4 = 128
#define LDS_CBUF_OFF 116864   // 512*4 = 2048
#define LDS_HSTG_OFF 118912   // 512*2 = 1024 (16B aligned)
#define LDS_TOTAL    119936

// workspace layout (bytes)
#define WS_XSWZ   0u          // T*B*I bf16 = 8388608
#define WS_HSWZ   8388608u    // 4 slots * 64*1024 bf16 = 524288
#define WS_CNT    8912896u    // 8 counters, 256B apart = 2048
#define WS_HLAST  8914944u    // 64*1024 f32 = 262144

__device__ __forceinline__ u16 f2bf(float f) {
    u32 u = __float_as_uint(f);
    u32 r = (u + 0x7fffu + ((u >> 16) & 1u)) >> 16;
    return (u16)r;
}
__device__ __forceinline__ float fsig(float x) { return 1.0f / (1.0f + __expf(-x)); }
__device__ __forceinline__ float ftanh(float x) { return 2.0f * fsig(2.0f * x) - 1.0f; }

union frag_u { i32x4 i; short8 s; };

// coherent (sc0 sc1) 16B h-frag load: volatile non-atomic -> streamed
// global_load_dwordx4 with cache-bypass bits; compiler-tracked (vmcnt, MLP).
__device__ __forceinline__ short8 load_hfrag(const u16* p) {
    frag_u u;
    u.i = *(const volatile i32x4*)p;
    return u.s;
}

// ---------------------------------------------------------------------------
// Pre-swizzle inputs [B][T][I] fp32 -> xswz[t] bf16 in MFMA-A-fragment layout:
// 16B unit index (per t): ((mt*8 + s)*4 + q)*16 + m  holds A[b=mt*16+m][k=s*32+q*8 .. +7]
// ---------------------------------------------------------------------------
extern "C" __global__ void prep_x(const float* __restrict__ in, u16* __restrict__ xswz) {
    int o = blockIdx.x * 256 + threadIdx.x;           // octet index, 524288 total
    int m = o & 15, q = (o >> 4) & 3, s = (o >> 6) & 7, mt = (o >> 9) & 3, t = o >> 11;
    int b = mt * 16 + m, k = s * 32 + q * 8;
    const float* src = in + ((size_t)(b * T_DIM + t)) * I_DIM + k;
    float4 v0 = *(const float4*)src;
    float4 v1 = *(const float4*)(src + 4);
    short8 val;
    val[0] = (short)f2bf(v0.x); val[1] = (short)f2bf(v0.y);
    val[2] = (short)f2bf(v0.z); val[3] = (short)f2bf(v0.w);
    val[4] = (short)f2bf(v1.x); val[5] = (short)f2bf(v1.y);
    val[6] = (short)f2bf(v1.z); val[7] = (short)f2bf(v1.w);
    *(short8*)(xswz + (size_t)o * 8) = val;
}

// ---------------------------------------------------------------------------
// Persistent LSTM scan: 128 WGs x 256 threads, 1 WG/CU. WG j owns units
// j*8..j*8+7 (32 gate rows). W slice in LDS (bf16, B-swizzled). 4-way K-split
// across waves; A-frags from global (pre-swizzled), issued upfront (40-deep
// MLP). KEY (r5): h traffic uses plain VOLATILE 16B vector ops (sc0 sc1,
// non-atomic) instead of 8B relaxed atomics -> streaming, not atomic-path.
// Sync: 8 monotonic counters (256B apart); producer fetch_add(1) after
// publish; wave0 polls, __syncthreads gates the WG.
// ---------------------------------------------------------------------------
extern "C" __global__ void __launch_bounds__(256, 1) lstm_scan(
    const u16* __restrict__ xswz, u16* hswz,
    const float* __restrict__ Wih, const float* __restrict__ Whh,
    const float* __restrict__ bih, const float* __restrict__ bhh,
    int* cnt8, float* hlast)
{
    extern __shared__ char lds[];
    u16*   Wlds   = (u16*)(lds + LDS_W_OFF);
    float* pacc   = (float*)(lds + LDS_PACC_OFF);
    float* bias   = (float*)(lds + LDS_BIAS_OFF);
    float* cbuf   = (float*)(lds + LDS_CBUF_OFF);
    u16*   hstage = (u16*)(lds + LDS_HSTG_OFF);

    const int j    = blockIdx.x;
    const int tid  = threadIdx.x;
    const int lane = tid & 63;
    const int w    = tid >> 6;

    // ---- stage W slice into LDS, bf16, B-swizzled:
    // unit wu = ((nt*40 + sg)*4 + q)*16 + nn  holds W[r(nt,nn)][sg*32+q*8 .. +7]
    for (int i = 0; i < 20; ++i) {
        int wu = tid + i * 256;
        int nn = wu & 15, q = (wu >> 4) & 3, rest = wu >> 6;
        int sg = rest % 40, nt = rest / 40;
        int n = nt * 16 + nn;
        int g = n >> 3, uu = n & 7;
        int r = g * H_DIM + j * UPW + uu;
        int kb = sg * 32 + q * 8;
        const float* src = (kb < I_DIM) ? (Wih + (size_t)r * I_DIM + kb)
                                        : (Whh + (size_t)r * H_DIM + (kb - I_DIM));
        short8 val;
        #pragma unroll
        for (int e = 0; e < 8; ++e) val[e] = (short)f2bf(src[e]);
        *(short8*)(Wlds + (size_t)wu * 8) = val;
    }
    if (tid < 32) {
        int n = tid, g = n >> 3, uu = n & 7;
        int r = g * H_DIM + j * UPW + uu;
        bias[n] = bih[r] + bhh[r];
    }
    for (int i = tid; i < 512; i += 256) cbuf[i] = 0.0f;
    __syncthreads();

    const int m16 = lane & 15, q4 = lane >> 4;

    for (int t = 0; t < T_DIM; ++t) {
        // ---- gate: wave0 polls the 8 counters; barrier releases the WG
        if (w == 0 && t > 0) {
            int target = 16 * t;
            const int* cp = cnt8 + (lane << 6);   // lane*256 bytes
            bool need = lane < 8;
            while (true) {
                int v = need ? __hip_atomic_load(cp, __ATOMIC_RELAXED,
                                                 __HIP_MEMORY_SCOPE_SYSTEM)
                             : 0x7fffffff;
                if (__all(v >= target)) break;
                __builtin_amdgcn_s_sleep(1);
            }
        }
        __syncthreads();   // (C) state t visible to whole WG

        const u16* xbase = xswz + (size_t)t * (B_DIM * I_DIM);
        const u16* hbase = hswz + (size_t)(t & 3) * (B_DIM * H_DIM);

        // ---- PHASE 1: issue ALL A-frag loads upfront (40 per lane)
        short8 a[10][4];
        if (w == 0) {
            // h-frags first (long latency), then cached x-frags
            #pragma unroll
            for (int ss = 8; ss < 10; ++ss) {
                int sgh = ss - 8;
                #pragma unroll
                for (int mt = 0; mt < 4; ++mt)
                    a[ss][mt] = load_hfrag(hbase + ((((mt * 32 + sgh) * 4) + q4) * 16 + m16) * 8);
            }
            #pragma unroll
            for (int ss = 0; ss < 8; ++ss) {
                #pragma unroll
                for (int mt = 0; mt < 4; ++mt)
                    a[ss][mt] = *(const short8*)(xbase + ((((mt * 8 + ss) * 4) + q4) * 16 + m16) * 8);
            }
        } else {
            #pragma unroll
            for (int ss = 0; ss < 10; ++ss) {
                int sgh = w * 10 + ss - 8;
                #pragma unroll
                for (int mt = 0; mt < 4; ++mt)
                    a[ss][mt] = load_hfrag(hbase + ((((mt * 32 + sgh) * 4) + q4) * 16 + m16) * 8);
            }
        }

        // ---- PHASE 2: MFMA loop consuming the register array
        floatx4 acc[4][2];
        #pragma unroll
        for (int mt = 0; mt < 4; ++mt)
            #pragma unroll
            for (int nt = 0; nt < 2; ++nt)
                acc[mt][nt] = (floatx4){0.f, 0.f, 0.f, 0.f};

        #pragma unroll
        for (int ss = 0; ss < 10; ++ss) {
            int sg = w * 10 + ss;
            short8 b[2];
            #pragma unroll
            for (int nt = 0; nt < 2; ++nt)
                b[nt] = *(const short8*)(Wlds + ((((nt * 40 + sg) * 4) + q4) * 16 + m16) * 8);
            #pragma unroll
            for (int mt = 0; mt < 4; ++mt)
                #pragma unroll
                for (int nt = 0; nt < 2; ++nt)
                    acc[mt][nt] = __builtin_amdgcn_mfma_f32_16x16x32_bf16(
                        a[ss][mt], b[nt], acc[mt][nt], 0, 0, 0);
        }

        // ---- write K-partials transposed: pacc[(w*32+n)*BSTR + b], b128 stores
        #pragma unroll
        for (int mt = 0; mt < 4; ++mt)
            #pragma unroll
            for (int nt = 0; nt < 2; ++nt)
                *(floatx4*)(pacc + (w * 32 + nt * 16 + m16) * BSTR + mt * 16 + q4 * 4) =
                    acc[mt][nt];
        __syncthreads();   // (A) pacc ready

        // ---- pointwise: reduce 4 partials, gates, c/h update -> hstage (LDS)
        #pragma unroll
        for (int it = 0; it < 2; ++it) {
            int idx = tid + it * 256;       // (b, uu)
            int b = idx >> 3, uu = idx & 7;
            float s[4];
            #pragma unroll
            for (int g = 0; g < 4; ++g) {
                int n = g * 8 + uu;
                float v = bias[n];
                #pragma unroll
                for (int ww = 0; ww < 4; ++ww) v += pacc[(ww * 32 + n) * BSTR + b];
                s[g] = v;
            }
            float ig = fsig(s[0]), fg = fsig(s[1]), gg = ftanh(s[2]), og = fsig(s[3]);
            float c = fg * cbuf[b * 8 + uu] + ig * gg;
            cbuf[b * 8 + uu] = c;
            float h = og * ftanh(c);
            hstage[b * 8 + uu] = f2bf(h);
            if (t == T_DIM - 1) hlast[b * H_DIM + j * UPW + uu] = h;
        }
        __syncthreads();   // (B) hstage ready; pacc free for next step

        // ---- publish: wave0, one volatile 16B store per lane, vmcnt(0), add
        if (tid < 64 && t + 1 < T_DIM) {
            int b = tid;
            i32x4 val = *((const i32x4*)hstage + b);
            u16* hw = hswz + (size_t)((t + 1) & 3) * (B_DIM * H_DIM);
            // unit octet: ((mt*32 + (j>>2))*4 + (j&3))*16 + mm, mt=b>>4, mm=b&15
            int unit = (((b >> 4) * 32 + (j >> 2)) * 4 + (j & 3)) * 16 + (b & 15);
            *((volatile i32x4*)hw + unit) = val;
            asm volatile("s_waitcnt vmcnt(0)" ::: "memory");  // h stores at L3
            if (tid == 0)
                __hip_atomic_fetch_add(cnt8 + ((j >> 4) << 6), 1, __ATOMIC_RELAXED,
                                       __HIP_MEMORY_SCOPE_SYSTEM);
        }
    }
}

// ---------------------------------------------------------------------------
// FC + log_softmax: one wave per batch row. logits[b][c] = h.fc_w[c] + fc_b[c]
// ---------------------------------------------------------------------------
extern "C" __global__ void fc_logsoftmax(const float* __restrict__ hlast,
                                         const float* __restrict__ fcw,
                                         const float* __restrict__ fcb,
                                         float* __restrict__ out)
{
    int b = blockIdx.x, c = threadIdx.x;  // 64 threads, 1 wave
    float acc = 0.0f;
    if (c < C_DIM) {
        const float* wr = fcw + (size_t)c * H_DIM;
        const float* hr = hlast + (size_t)b * H_DIM;
        for (int k = 0; k < H_DIM; k += 4) {
            float4 hv = *(const float4*)(hr + k);
            float4 wv = *(const float4*)(wr + k);
            acc += hv.x * wv.x + hv.y * wv.y + hv.z * wv.z + hv.w * wv.w;
        }
        acc += fcb[c];
    }
    float logit = (c < C_DIM) ? acc : -1e30f;
    float mx = logit;
    #pragma unroll
    for (int off = 32; off; off >>= 1) mx = fmaxf(mx, __shfl_xor(mx, off));
    float e = (c < C_DIM) ? expf(logit - mx) : 0.0f;
    float sum = e;
    #pragma unroll
    for (int off = 32; off; off >>= 1) sum += __shfl_xor(sum, off);
    if (c < C_DIM) out[b * C_DIM + c] = logit - mx - logf(sum);
}

extern "C" void kernel_launch(void* const* d_in, const int* in_sizes, int n_in,
                              void* d_out, int out_size, void* d_ws, size_t ws_size,
                              hipStream_t stream)
{
    const float* inputs = (const float*)d_in[0];
    const float* Wih    = (const float*)d_in[1];
    const float* Whh    = (const float*)d_in[2];
    const float* bih    = (const float*)d_in[3];
    const float* bhh    = (const float*)d_in[4];
    const float* fcw    = (const float*)d_in[5];
    const float* fcb    = (const float*)d_in[6];
    float* out = (float*)d_out;

    char* ws = (char*)d_ws;
    u16*   xswz  = (u16*)(ws + WS_XSWZ);
    u16*   hswz  = (u16*)(ws + WS_HSWZ);
    int*   cnt8  = (int*)(ws + WS_CNT);
    float* hlast = (float*)(ws + WS_HLAST);

    // h_0 = 0 (slot 0) and counters = 0 — every launch (graph-safe async)
    hipMemsetAsync(hswz, 0, B_DIM * H_DIM * sizeof(u16), stream);
    hipMemsetAsync(cnt8, 0, 2048, stream);

    prep_x<<<2048, 256, 0, stream>>>(inputs, xswz);

    (void)hipFuncSetAttribute((const void*)lstm_scan,
                              hipFuncAttributeMaxDynamicSharedMemorySize, LDS_TOTAL);
    lstm_scan<<<NWG, 256, LDS_TOTAL, stream>>>(xswz, hswz, Wih, Whh, bih, bhh,
                                               cnt8, hlast);
    fc_logsoftmax<<<B_DIM, 64, 0, stream>>>(hlast, fcw, fcb, out);
}

// Round 6
// 2308.980 us; speedup vs baseline: 1.7459x; 1.7459x over previous
//
#include <hip/hip_runtime.h>
#include <hip/hip_bf16.h>

typedef unsigned short u16;
typedef unsigned int u32;
typedef unsigned long long u64;
typedef __attribute__((ext_vector_type(8))) short short8;
typedef __attribute__((ext_vector_type(4))) float floatx4;

#define I_DIM 256
#define H_DIM 1024
#define B_DIM 64
#define T_DIM 256
#define C_DIM 60
#define NWG   128
#define UPW   8      // hidden units per WG
#define BSTR  68     // pacc row stride (dwords): 16B-aligned, 2-way read aliasing

// LDS layout (bytes)
#define LDS_W_OFF    0        // 2*40*4*16 frags * 16B = 81920
#define LDS_PACC_OFF 81920    // 128 rows * 68 dw * 4B = 34816
#define LDS_BIAS_OFF 116736   // 32*4 = 128
#define LDS_CBUF_OFF 116864   // 512*4 = 2048
#define LDS_HSTG_OFF 118912   // 512*2 = 1024 (16B aligned)
#define LDS_TOTAL    119936

// workspace layout (bytes)
#define WS_XSWZ   0u          // T*B*I bf16 = 8388608
#define WS_HSWZ   8388608u    // 4 slots * 64*1024 bf16 = 524288
#define WS_HLAST  8912896u    // 64*1024 f32 = 262144

#define LSBM 0x0001000100010001ull

__device__ __forceinline__ u16 f2bf(float f) {
    u32 u = __float_as_uint(f);
    u32 r = (u + 0x7fffu + ((u >> 16) & 1u)) >> 16;
    return (u16)r;
}
__device__ __forceinline__ float fsig(float x) { return 1.0f / (1.0f + __expf(-x)); }
__device__ __forceinline__ float ftanh(float x) { return 2.0f * fsig(2.0f * x) - 1.0f; }

union hfrag { short8 s; u64 q[2]; };

// ---------------------------------------------------------------------------
// Pre-swizzle inputs [B][T][I] fp32 -> xswz[t] bf16 in MFMA-A-fragment layout:
// 16B unit index (per t): ((mt*8 + s)*4 + q)*16 + m  holds A[b=mt*16+m][k=s*32+q*8 .. +7]
// ---------------------------------------------------------------------------
extern "C" __global__ void prep_x(const float* __restrict__ in, u16* __restrict__ xswz) {
    int o = blockIdx.x * 256 + threadIdx.x;           // octet index, 524288 total
    int m = o & 15, q = (o >> 4) & 3, s = (o >> 6) & 7, mt = (o >> 9) & 3, t = o >> 11;
    int b = mt * 16 + m, k = s * 32 + q * 8;
    const float* src = in + ((size_t)(b * T_DIM + t)) * I_DIM + k;
    float4 v0 = *(const float4*)src;
    float4 v1 = *(const float4*)(src + 4);
    short8 val;
    val[0] = (short)f2bf(v0.x); val[1] = (short)f2bf(v0.y);
    val[2] = (short)f2bf(v0.z); val[3] = (short)f2bf(v0.w);
    val[4] = (short)f2bf(v1.x); val[5] = (short)f2bf(v1.y);
    val[6] = (short)f2bf(v1.z); val[7] = (short)f2bf(v1.w);
    *(short8*)(xswz + (size_t)o * 8) = val;
}

// ---------------------------------------------------------------------------
// Persistent LSTM scan, TAG-SYNCHRONIZED (r6): no flags, no counters, no
// producer-side waits. Each published bf16 h element carries a stolen lsb:
// lsb(uu) = bit (uu&3) of (t&15). An 8B half-frag self-validates: fresh iff
// its 4 lsbs == t&15. Producer fire-and-forget 8B atomic stores; consumers
// load (relaxed SYSTEM atomics, full MLP), validate in registers, batch-
// reload stale units. Slot rotation (mod 4) + nibble (mod 16) separates all
// reachable stale states; all-4-slot memset handles init/poison.
// Spread invariant: every WG's waves jointly need all 128 producers/step.
// ---------------------------------------------------------------------------
extern "C" __global__ void __launch_bounds__(256, 1) lstm_scan(
    const u16* __restrict__ xswz, u16* hswz,
    const float* __restrict__ Wih, const float* __restrict__ Whh,
    const float* __restrict__ bih, const float* __restrict__ bhh,
    float* hlast)
{
    extern __shared__ char lds[];
    u16*   Wlds   = (u16*)(lds + LDS_W_OFF);
    float* pacc   = (float*)(lds + LDS_PACC_OFF);
    float* bias   = (float*)(lds + LDS_BIAS_OFF);
    float* cbuf   = (float*)(lds + LDS_CBUF_OFF);
    u16*   hstage = (u16*)(lds + LDS_HSTG_OFF);

    const int j    = blockIdx.x;
    const int tid  = threadIdx.x;
    const int lane = tid & 63;
    const int w    = tid >> 6;

    // ---- stage W slice into LDS, bf16, B-swizzled:
    // unit wu = ((nt*40 + sg)*4 + q)*16 + nn  holds W[r(nt,nn)][sg*32+q*8 .. +7]
    for (int i = 0; i < 20; ++i) {
        int wu = tid + i * 256;
        int nn = wu & 15, q = (wu >> 4) & 3, rest = wu >> 6;
        int sg = rest % 40, nt = rest / 40;
        int n = nt * 16 + nn;
        int g = n >> 3, uu = n & 7;
        int r = g * H_DIM + j * UPW + uu;
        int kb = sg * 32 + q * 8;
        const float* src = (kb < I_DIM) ? (Wih + (size_t)r * I_DIM + kb)
                                        : (Whh + (size_t)r * H_DIM + (kb - I_DIM));
        short8 val;
        #pragma unroll
        for (int e = 0; e < 8; ++e) val[e] = (short)f2bf(src[e]);
        *(short8*)(Wlds + (size_t)wu * 8) = val;
    }
    if (tid < 32) {
        int n = tid, g = n >> 3, uu = n & 7;
        int r = g * H_DIM + j * UPW + uu;
        bias[n] = bih[r] + bhh[r];
    }
    for (int i = tid; i < 512; i += 256) cbuf[i] = 0.0f;
    __syncthreads();

    const int m16 = lane & 15, q4 = lane >> 4;

    for (int t = 0; t < T_DIM; ++t) {
        const u16* xbase = xswz + (size_t)t * (B_DIM * I_DIM);
        const u64* hq    = (const u64*)(hswz + (size_t)(t & 3) * (B_DIM * H_DIM));
        const int  En    = t & 15;
        const u64  Eq    = (u64)(En & 1) | ((u64)((En >> 1) & 1) << 16)
                         | ((u64)((En >> 2) & 1) << 32) | ((u64)((En >> 3) & 1) << 48);

        // ---- PHASE 1: issue all A-frag loads (x cached; h relaxed atomics)
        hfrag a[10][4];
        #pragma unroll
        for (int ss = 0; ss < 10; ++ss) {
            const int sg = w * 10 + ss;
            if (sg < 8) {      // x part (wave0 only; wave-uniform branch)
                #pragma unroll
                for (int mt = 0; mt < 4; ++mt)
                    a[ss][mt].s = *(const short8*)(xbase + ((((mt * 8 + sg) * 4) + q4) * 16 + m16) * 8);
            } else {           // h part: coherent atomic 8B pairs
                const int sgh = sg - 8;
                #pragma unroll
                for (int mt = 0; mt < 4; ++mt) {
                    const u64* p = hq + ((((mt * 32 + sgh) * 4) + q4) * 16 + m16) * 2;
                    a[ss][mt].q[0] = __hip_atomic_load(p,     __ATOMIC_RELAXED, __HIP_MEMORY_SCOPE_SYSTEM);
                    a[ss][mt].q[1] = __hip_atomic_load(p + 1, __ATOMIC_RELAXED, __HIP_MEMORY_SCOPE_SYSTEM);
                }
            }
        }

        // ---- validate tags; batch-reload stale units until all fresh
        u64 m = 0;
        #pragma unroll
        for (int ss = 0; ss < 10; ++ss) {
            if (w * 10 + ss >= 8) {
                #pragma unroll
                for (int mt = 0; mt < 4; ++mt)
                    if ((((a[ss][mt].q[0] ^ Eq) | (a[ss][mt].q[1] ^ Eq)) & LSBM) != 0)
                        m |= 1ull << (ss * 4 + mt);
            }
        }
        while (__any(m != 0)) {
            #pragma unroll
            for (int ss = 0; ss < 10; ++ss) {
                const int sg = w * 10 + ss;
                if (sg >= 8) {
                    const int sgh = sg - 8;
                    #pragma unroll
                    for (int mt = 0; mt < 4; ++mt)
                        if ((m >> (ss * 4 + mt)) & 1) {
                            const u64* p = hq + ((((mt * 32 + sgh) * 4) + q4) * 16 + m16) * 2;
                            a[ss][mt].q[0] = __hip_atomic_load(p,     __ATOMIC_RELAXED, __HIP_MEMORY_SCOPE_SYSTEM);
                            a[ss][mt].q[1] = __hip_atomic_load(p + 1, __ATOMIC_RELAXED, __HIP_MEMORY_SCOPE_SYSTEM);
                        }
                }
            }
            #pragma unroll
            for (int ss = 0; ss < 10; ++ss) {
                if (w * 10 + ss >= 8) {
                    #pragma unroll
                    for (int mt = 0; mt < 4; ++mt)
                        if (((m >> (ss * 4 + mt)) & 1) &&
                            ((((a[ss][mt].q[0] ^ Eq) | (a[ss][mt].q[1] ^ Eq)) & LSBM) == 0))
                            m &= ~(1ull << (ss * 4 + mt));
                }
            }
        }

        // ---- PHASE 2: MFMA loop consuming the register array
        floatx4 acc[4][2];
        #pragma unroll
        for (int mt = 0; mt < 4; ++mt)
            #pragma unroll
            for (int nt = 0; nt < 2; ++nt)
                acc[mt][nt] = (floatx4){0.f, 0.f, 0.f, 0.f};

        #pragma unroll
        for (int ss = 0; ss < 10; ++ss) {
            int sg = w * 10 + ss;
            short8 b[2];
            #pragma unroll
            for (int nt = 0; nt < 2; ++nt)
                b[nt] = *(const short8*)(Wlds + ((((nt * 40 + sg) * 4) + q4) * 16 + m16) * 8);
            #pragma unroll
            for (int mt = 0; mt < 4; ++mt)
                #pragma unroll
                for (int nt = 0; nt < 2; ++nt)
                    acc[mt][nt] = __builtin_amdgcn_mfma_f32_16x16x32_bf16(
                        a[ss][mt].s, b[nt], acc[mt][nt], 0, 0, 0);
        }

        // ---- write K-partials transposed: pacc[(w*32+n)*BSTR + b], b128 stores
        #pragma unroll
        for (int mt = 0; mt < 4; ++mt)
            #pragma unroll
            for (int nt = 0; nt < 2; ++nt)
                *(floatx4*)(pacc + (w * 32 + nt * 16 + m16) * BSTR + mt * 16 + q4 * 4) =
                    acc[mt][nt];
        __syncthreads();   // (A) pacc ready

        // ---- pointwise: reduce partials, gates, c/h update -> hstage (tagged)
        const int Ep = (t + 1) & 15;
        #pragma unroll
        for (int it = 0; it < 2; ++it) {
            int idx = tid + it * 256;       // (b, uu)
            int b = idx >> 3, uu = idx & 7;
            float s[4];
            #pragma unroll
            for (int g = 0; g < 4; ++g) {
                int n = g * 8 + uu;
                float v = bias[n];
                #pragma unroll
                for (int ww = 0; ww < 4; ++ww) v += pacc[(ww * 32 + n) * BSTR + b];
                s[g] = v;
            }
            float ig = fsig(s[0]), fg = fsig(s[1]), gg = ftanh(s[2]), og = fsig(s[3]);
            float c = fg * cbuf[b * 8 + uu] + ig * gg;
            cbuf[b * 8 + uu] = c;
            float h = og * ftanh(c);
            // steal lsb: tag bit (uu&3) of next step's nibble
            hstage[b * 8 + uu] = (u16)((f2bf(h) & 0xFFFEu) | ((Ep >> (uu & 3)) & 1));
            if (t == T_DIM - 1) hlast[b * H_DIM + j * UPW + uu] = h;
        }
        __syncthreads();   // (B) hstage ready; pacc free for next step

        // ---- publish: wave0, fire-and-forget 8B atomic stores; no wait
        if (tid < 64 && t + 1 < T_DIM) {
            int b = tid;
            const u64* hs = (const u64*)hstage;
            u64 lo = hs[b * 2], hi = hs[b * 2 + 1];
            u16* hw = hswz + (size_t)((t + 1) & 3) * (B_DIM * H_DIM);
            // unit octet: ((mt*32 + (j>>2))*4 + (j&3))*16 + mm, mt=b>>4, mm=b&15
            u64* dst = (u64*)hw + ((((b >> 4) * 32 + (j >> 2)) * 4 + (j & 3)) * 16 + (b & 15)) * 2;
            __hip_atomic_store(dst,     lo, __ATOMIC_RELAXED, __HIP_MEMORY_SCOPE_SYSTEM);
            __hip_atomic_store(dst + 1, hi, __ATOMIC_RELAXED, __HIP_MEMORY_SCOPE_SYSTEM);
        }
    }
}

// ---------------------------------------------------------------------------
// FC + log_softmax: one wave per batch row. logits[b][c] = h.fc_w[c] + fc_b[c]
// ---------------------------------------------------------------------------
extern "C" __global__ void fc_logsoftmax(const float* __restrict__ hlast,
                                         const float* __restrict__ fcw,
                                         const float* __restrict__ fcb,
                                         float* __restrict__ out)
{
    int b = blockIdx.x, c = threadIdx.x;  // 64 threads, 1 wave
    float acc = 0.0f;
    if (c < C_DIM) {
        const float* wr = fcw + (size_t)c * H_DIM;
        const float* hr = hlast + (size_t)b * H_DIM;
        for (int k = 0; k < H_DIM; k += 4) {
            float4 hv = *(const float4*)(hr + k);
            float4 wv = *(const float4*)(wr + k);
            acc += hv.x * wv.x + hv.y * wv.y + hv.z * wv.z + hv.w * wv.w;
        }
        acc += fcb[c];
    }
    float logit = (c < C_DIM) ? acc : -1e30f;
    float mx = logit;
    #pragma unroll
    for (int off = 32; off; off >>= 1) mx = fmaxf(mx, __shfl_xor(mx, off));
    float e = (c < C_DIM) ? expf(logit - mx) : 0.0f;
    float sum = e;
    #pragma unroll
    for (int off = 32; off; off >>= 1) sum += __shfl_xor(sum, off);
    if (c < C_DIM) out[b * C_DIM + c] = logit - mx - logf(sum);
}

extern "C" void kernel_launch(void* const* d_in, const int* in_sizes, int n_in,
                              void* d_out, int out_size, void* d_ws, size_t ws_size,
                              hipStream_t stream)
{
    const float* inputs = (const float*)d_in[0];
    const float* Wih    = (const float*)d_in[1];
    const float* Whh    = (const float*)d_in[2];
    const float* bih    = (const float*)d_in[3];
    const float* bhh    = (const float*)d_in[4];
    const float* fcw    = (const float*)d_in[5];
    const float* fcb    = (const float*)d_in[6];
    float* out = (float*)d_out;

    char* ws = (char*)d_ws;
    u16*   xswz  = (u16*)(ws + WS_XSWZ);
    u16*   hswz  = (u16*)(ws + WS_HSWZ);
    float* hlast = (float*)(ws + WS_HLAST);

    // zero ALL 4 h slots each launch: slot0 = h_0 = 0 with tag 0 (valid at
    // t=0); slots 1-3 zero tags != 1..15 -> stale until overwritten.
    hipMemsetAsync(hswz, 0, 4 * B_DIM * H_DIM * sizeof(u16), stream);

    prep_x<<<2048, 256, 0, stream>>>(inputs, xswz);

    (void)hipFuncSetAttribute((const void*)lstm_scan,
                              hipFuncAttributeMaxDynamicSharedMemorySize, LDS_TOTAL);
    lstm_scan<<<NWG, 256, LDS_TOTAL, stream>>>(xswz, hswz, Wih, Whh, bih, bhh,
                                               hlast);
    fc_logsoftmax<<<B_DIM, 64, 0, stream>>>(hlast, fcw, fcb, out);
}

// Round 7
// 1958.052 us; speedup vs baseline: 2.0588x; 1.1792x over previous
//
#include <hip/hip_runtime.h>
#include <hip/hip_bf16.h>

typedef unsigned short u16;
typedef unsigned int u32;
typedef unsigned long long u64;
typedef __attribute__((ext_vector_type(8))) short short8;
typedef __attribute__((ext_vector_type(4))) float floatx4;

#define I_DIM 256
#define H_DIM 1024
#define B_DIM 64
#define T_DIM 256
#define C_DIM 60
#define NWG   128
#define UPW   8      // hidden units per WG
#define BSTR  68     // pacc row stride (dwords): 16B-aligned, 2-way read aliasing
#define NSLOT 15     // h ring slots (coprime with tag period 13)

// LDS layout (bytes)
#define LDS_W_OFF    0        // 2*40*4*16 frags * 16B = 81920
#define LDS_PACC_OFF 81920    // 128 rows * 68 dw * 4B = 34816
#define LDS_BIAS_OFF 116736   // 32*4 = 128
#define LDS_CBUF_OFF 116864   // 512*4 = 2048
#define LDS_HSTG_OFF 118912   // 512*2 = 1024 (16B aligned)
#define LDS_TOTAL    119936

// workspace layout (bytes)
#define WS_XSWZ   0u          // T*B*I bf16 = 8388608
#define WS_HSWZ   8388608u    // 15 slots * 64*1024 bf16 = 1966080
#define WS_CNT    10354688u   // 8 counters, 256B apart = 2048
#define WS_HLAST  10356736u   // 64*1024 f32 = 262144

#define LSBM 0x0001000100010001ull

__device__ __forceinline__ u16 f2bf(float f) {
    u32 u = __float_as_uint(f);
    u32 r = (u + 0x7fffu + ((u >> 16) & 1u)) >> 16;
    return (u16)r;
}
__device__ __forceinline__ float fsig(float x) { return 1.0f / (1.0f + __expf(-x)); }
__device__ __forceinline__ float ftanh(float x) { return 2.0f * fsig(2.0f * x) - 1.0f; }

union hfrag { short8 s; u64 q[2]; };

// ---------------------------------------------------------------------------
// Pre-swizzle inputs [B][T][I] fp32 -> xswz[t] bf16 in MFMA-A-fragment layout:
// 16B unit index (per t): ((mt*8 + s)*4 + q)*16 + m  holds A[b=mt*16+m][k=s*32+q*8 .. +7]
// ---------------------------------------------------------------------------
extern "C" __global__ void prep_x(const float* __restrict__ in, u16* __restrict__ xswz) {
    int o = blockIdx.x * 256 + threadIdx.x;           // octet index, 524288 total
    int m = o & 15, q = (o >> 4) & 3, s = (o >> 6) & 7, mt = (o >> 9) & 3, t = o >> 11;
    int b = mt * 16 + m, k = s * 32 + q * 8;
    const float* src = in + ((size_t)(b * T_DIM + t)) * I_DIM + k;
    float4 v0 = *(const float4*)src;
    float4 v1 = *(const float4*)(src + 4);
    short8 val;
    val[0] = (short)f2bf(v0.x); val[1] = (short)f2bf(v0.y);
    val[2] = (short)f2bf(v0.z); val[3] = (short)f2bf(v0.w);
    val[4] = (short)f2bf(v1.x); val[5] = (short)f2bf(v1.y);
    val[6] = (short)f2bf(v1.z); val[7] = (short)f2bf(v1.w);
    *(short8*)(xswz + (size_t)o * 8) = val;
}

// ---------------------------------------------------------------------------
// Persistent LSTM scan (r7): GATED CACHED BROADCAST.
// h consumers use normal CACHED vector loads -> 16 WGs per XCD share lines in
// their L2 (L3 traffic 1 MB/step, not 16 MB). Freshness is guaranteed by the
// counter gate: producers sc-store h, wait vmcnt(0) (data at L3), fetch_add;
// wave0 polls 8 counters before any consumer load is issued, so every L2
// demand-miss pulls fresh data. Residual stale-L2/L1 hits (line surviving
// >= 15 steps) are caught by stolen-lsb tags (tag=(t%13)+1, never 0=poison;
// 15 slots, periods coprime -> all stale generations detected) and repaired
// via sc-retry loads. Upfront 40-deep load MLP retained from r4.
// ---------------------------------------------------------------------------
extern "C" __global__ void __launch_bounds__(256, 1) lstm_scan(
    const u16* __restrict__ xswz, u16* hswz,
    const float* __restrict__ Wih, const float* __restrict__ Whh,
    const float* __restrict__ bih, const float* __restrict__ bhh,
    int* cnt8, float* hlast)
{
    extern __shared__ char lds[];
    u16*   Wlds   = (u16*)(lds + LDS_W_OFF);
    float* pacc   = (float*)(lds + LDS_PACC_OFF);
    float* bias   = (float*)(lds + LDS_BIAS_OFF);
    float* cbuf   = (float*)(lds + LDS_CBUF_OFF);
    u16*   hstage = (u16*)(lds + LDS_HSTG_OFF);

    const int j    = blockIdx.x;
    const int tid  = threadIdx.x;
    const int lane = tid & 63;
    const int w    = tid >> 6;

    // ---- stage W slice into LDS, bf16, B-swizzled:
    // unit wu = ((nt*40 + sg)*4 + q)*16 + nn  holds W[r(nt,nn)][sg*32+q*8 .. +7]
    for (int i = 0; i < 20; ++i) {
        int wu = tid + i * 256;
        int nn = wu & 15, q = (wu >> 4) & 3, rest = wu >> 6;
        int sg = rest % 40, nt = rest / 40;
        int n = nt * 16 + nn;
        int g = n >> 3, uu = n & 7;
        int r = g * H_DIM + j * UPW + uu;
        int kb = sg * 32 + q * 8;
        const float* src = (kb < I_DIM) ? (Wih + (size_t)r * I_DIM + kb)
                                        : (Whh + (size_t)r * H_DIM + (kb - I_DIM));
        short8 val;
        #pragma unroll
        for (int e = 0; e < 8; ++e) val[e] = (short)f2bf(src[e]);
        *(short8*)(Wlds + (size_t)wu * 8) = val;
    }
    if (tid < 32) {
        int n = tid, g = n >> 3, uu = n & 7;
        int r = g * H_DIM + j * UPW + uu;
        bias[n] = bih[r] + bhh[r];
    }
    for (int i = tid; i < 512; i += 256) cbuf[i] = 0.0f;
    __syncthreads();

    const int m16 = lane & 15, q4 = lane >> 4;

    for (int t = 0; t < T_DIM; ++t) {
        // ---- gate: wave0 polls the 8 counters (h(t) at L3 once passed)
        if (w == 0 && t > 0) {
            int target = 16 * t;
            const int* cp = cnt8 + (lane << 6);   // lane*256 bytes
            bool need = lane < 8;
            while (true) {
                int v = need ? __hip_atomic_load(cp, __ATOMIC_RELAXED,
                                                 __HIP_MEMORY_SCOPE_SYSTEM)
                             : 0x7fffffff;
                if (__all(v >= target)) break;
                __builtin_amdgcn_s_sleep(1);
            }
        }
        __syncthreads();   // (C) gate passed for whole WG

        const u16* xbase = xswz + (size_t)t * (B_DIM * I_DIM);
        const u16* hbase = hswz + (size_t)(t % NSLOT) * (B_DIM * H_DIM);
        const int  En    = (t % 13) + 1;          // tag nibble, never 0
        const u64  Eq    = (u64)(En & 1) | ((u64)((En >> 1) & 1) << 16)
                         | ((u64)((En >> 2) & 1) << 32) | ((u64)((En >> 3) & 1) << 48);

        // ---- PHASE 1: upfront loads — x and h both CACHED vector loads
        hfrag a[10][4];
        #pragma unroll
        for (int ss = 0; ss < 10; ++ss) {
            const int sg = w * 10 + ss;
            if (sg < 8) {      // x part (wave0 only; wave-uniform branch)
                #pragma unroll
                for (int mt = 0; mt < 4; ++mt)
                    a[ss][mt].s = *(const short8*)(xbase + ((((mt * 8 + sg) * 4) + q4) * 16 + m16) * 8);
            } else {           // h part: cached (L2-shared across the XCD)
                const int sgh = sg - 8;
                #pragma unroll
                for (int mt = 0; mt < 4; ++mt)
                    a[ss][mt].s = *(const short8*)(hbase + ((((mt * 32 + sgh) * 4) + q4) * 16 + m16) * 8);
            }
        }

        // ---- validate tags (t>0); rare stale hits repaired via sc loads
        if (t > 0) {
            u64 m = 0;
            #pragma unroll
            for (int ss = 0; ss < 10; ++ss) {
                if (w * 10 + ss >= 8) {
                    #pragma unroll
                    for (int mt = 0; mt < 4; ++mt)
                        if ((((a[ss][mt].q[0] ^ Eq) | (a[ss][mt].q[1] ^ Eq)) & LSBM) != 0)
                            m |= 1ull << (ss * 4 + mt);
                }
            }
            while (__any(m != 0)) {
                #pragma unroll
                for (int ss = 0; ss < 10; ++ss) {
                    const int sg = w * 10 + ss;
                    if (sg >= 8) {
                        const int sgh = sg - 8;
                        #pragma unroll
                        for (int mt = 0; mt < 4; ++mt)
                            if ((m >> (ss * 4 + mt)) & 1) {
                                const u64* p = (const u64*)hbase
                                    + ((((mt * 32 + sgh) * 4) + q4) * 16 + m16) * 2;
                                a[ss][mt].q[0] = __hip_atomic_load(p,     __ATOMIC_RELAXED, __HIP_MEMORY_SCOPE_SYSTEM);
                                a[ss][mt].q[1] = __hip_atomic_load(p + 1, __ATOMIC_RELAXED, __HIP_MEMORY_SCOPE_SYSTEM);
                            }
                    }
                }
                #pragma unroll
                for (int ss = 0; ss < 10; ++ss) {
                    if (w * 10 + ss >= 8) {
                        #pragma unroll
                        for (int mt = 0; mt < 4; ++mt)
                            if (((m >> (ss * 4 + mt)) & 1) &&
                                ((((a[ss][mt].q[0] ^ Eq) | (a[ss][mt].q[1] ^ Eq)) & LSBM) == 0))
                                m &= ~(1ull << (ss * 4 + mt));
                    }
                }
            }
        }

        // ---- PHASE 2: MFMA loop consuming the register array
        floatx4 acc[4][2];
        #pragma unroll
        for (int mt = 0; mt < 4; ++mt)
            #pragma unroll
            for (int nt = 0; nt < 2; ++nt)
                acc[mt][nt] = (floatx4){0.f, 0.f, 0.f, 0.f};

        #pragma unroll
        for (int ss = 0; ss < 10; ++ss) {
            int sg = w * 10 + ss;
            short8 b[2];
            #pragma unroll
            for (int nt = 0; nt < 2; ++nt)
                b[nt] = *(const short8*)(Wlds + ((((nt * 40 + sg) * 4) + q4) * 16 + m16) * 8);
            #pragma unroll
            for (int mt = 0; mt < 4; ++mt)
                #pragma unroll
                for (int nt = 0; nt < 2; ++nt)
                    acc[mt][nt] = __builtin_amdgcn_mfma_f32_16x16x32_bf16(
                        a[ss][mt].s, b[nt], acc[mt][nt], 0, 0, 0);
        }

        // ---- write K-partials transposed: pacc[(w*32+n)*BSTR + b], b128 stores
        #pragma unroll
        for (int mt = 0; mt < 4; ++mt)
            #pragma unroll
            for (int nt = 0; nt < 2; ++nt)
                *(floatx4*)(pacc + (w * 32 + nt * 16 + m16) * BSTR + mt * 16 + q4 * 4) =
                    acc[mt][nt];
        __syncthreads();   // (A) pacc ready

        // ---- pointwise: reduce partials, gates, c/h update -> hstage (tagged)
        const int Ep = ((t + 1) % 13) + 1;
        #pragma unroll
        for (int it = 0; it < 2; ++it) {
            int idx = tid + it * 256;       // (b, uu)
            int b = idx >> 3, uu = idx & 7;
            float s[4];
            #pragma unroll
            for (int g = 0; g < 4; ++g) {
                int n = g * 8 + uu;
                float v = bias[n];
                #pragma unroll
                for (int ww = 0; ww < 4; ++ww) v += pacc[(ww * 32 + n) * BSTR + b];
                s[g] = v;
            }
            float ig = fsig(s[0]), fg = fsig(s[1]), gg = ftanh(s[2]), og = fsig(s[3]);
            float c = fg * cbuf[b * 8 + uu] + ig * gg;
            cbuf[b * 8 + uu] = c;
            float h = og * ftanh(c);
            // steal lsb: tag bit (uu&3) of next step's nibble
            hstage[b * 8 + uu] = (u16)((f2bf(h) & 0xFFFEu) | ((Ep >> (uu & 3)) & 1));
            if (t == T_DIM - 1) hlast[b * H_DIM + j * UPW + uu] = h;
        }
        __syncthreads();   // (B) hstage ready; pacc free for next step

        // ---- publish: wave0 sc-stores h(t+1), vmcnt(0) (at L3), fetch_add
        if (tid < 64 && t + 1 < T_DIM) {
            int b = tid;
            const u64* hs = (const u64*)hstage;
            u64 lo = hs[b * 2], hi = hs[b * 2 + 1];
            u16* hw = hswz + (size_t)((t + 1) % NSLOT) * (B_DIM * H_DIM);
            // unit octet: ((mt*32 + (j>>2))*4 + (j&3))*16 + mm, mt=b>>4, mm=b&15
            u64* dst = (u64*)hw + ((((b >> 4) * 32 + (j >> 2)) * 4 + (j & 3)) * 16 + (b & 15)) * 2;
            __hip_atomic_store(dst,     lo, __ATOMIC_RELAXED, __HIP_MEMORY_SCOPE_SYSTEM);
            __hip_atomic_store(dst + 1, hi, __ATOMIC_RELAXED, __HIP_MEMORY_SCOPE_SYSTEM);
            asm volatile("s_waitcnt vmcnt(0)" ::: "memory");  // h at L3
            if (tid == 0)
                __hip_atomic_fetch_add(cnt8 + ((j >> 4) << 6), 1, __ATOMIC_RELAXED,
                                       __HIP_MEMORY_SCOPE_SYSTEM);
        }
    }
}

// ---------------------------------------------------------------------------
// FC + log_softmax: one wave per batch row. logits[b][c] = h.fc_w[c] + fc_b[c]
// ---------------------------------------------------------------------------
extern "C" __global__ void fc_logsoftmax(const float* __restrict__ hlast,
                                         const float* __restrict__ fcw,
                                         const float* __restrict__ fcb,
                                         float* __restrict__ out)
{
    int b = blockIdx.x, c = threadIdx.x;  // 64 threads, 1 wave
    float acc = 0.0f;
    if (c < C_DIM) {
        const float* wr = fcw + (size_t)c * H_DIM;
        const float* hr = hlast + (size_t)b * H_DIM;
        for (int k = 0; k < H_DIM; k += 4) {
            float4 hv = *(const float4*)(hr + k);
            float4 wv = *(const float4*)(wr + k);
            acc += hv.x * wv.x + hv.y * wv.y + hv.z * wv.z + hv.w * wv.w;
        }
        acc += fcb[c];
    }
    float logit = (c < C_DIM) ? acc : -1e30f;
    float mx = logit;
    #pragma unroll
    for (int off = 32; off; off >>= 1) mx = fmaxf(mx, __shfl_xor(mx, off));
    float e = (c < C_DIM) ? expf(logit - mx) : 0.0f;
    float sum = e;
    #pragma unroll
    for (int off = 32; off; off >>= 1) sum += __shfl_xor(sum, off);
    if (c < C_DIM) out[b * C_DIM + c] = logit - mx - logf(sum);
}

extern "C" void kernel_launch(void* const* d_in, const int* in_sizes, int n_in,
                              void* d_out, int out_size, void* d_ws, size_t ws_size,
                              hipStream_t stream)
{
    const float* inputs = (const float*)d_in[0];
    const float* Wih    = (const float*)d_in[1];
    const float* Whh    = (const float*)d_in[2];
    const float* bih    = (const float*)d_in[3];
    const float* bhh    = (const float*)d_in[4];
    const float* fcw    = (const float*)d_in[5];
    const float* fcb    = (const float*)d_in[6];
    float* out = (float*)d_out;

    char* ws = (char*)d_ws;
    u16*   xswz  = (u16*)(ws + WS_XSWZ);
    u16*   hswz  = (u16*)(ws + WS_HSWZ);
    int*   cnt8  = (int*)(ws + WS_CNT);
    float* hlast = (float*)(ws + WS_HLAST);

    // slot 0 = h_0 = 0 (t=0 skips tag check); counters = 0. Kernel-boundary
    // acquire/release makes these visible to all cached readers.
    hipMemsetAsync(hswz, 0, B_DIM * H_DIM * sizeof(u16), stream);
    hipMemsetAsync(cnt8, 0, 2048, stream);

    prep_x<<<2048, 256, 0, stream>>>(inputs, xswz);

    (void)hipFuncSetAttribute((const void*)lstm_scan,
                              hipFuncAttributeMaxDynamicSharedMemorySize, LDS_TOTAL);
    lstm_scan<<<NWG, 256, LDS_TOTAL, stream>>>(xswz, hswz, Wih, Whh, bih, bhh,
                                               cnt8, hlast);
    fc_logsoftmax<<<B_DIM, 64, 0, stream>>>(hlast, fcw, fcb, out);
}

// Round 8
// 1575.422 us; speedup vs baseline: 2.5588x; 1.2429x over previous
//
#include <hip/hip_runtime.h>
#include <hip/hip_bf16.h>

typedef unsigned short u16;
typedef unsigned int u32;
typedef unsigned long long u64;
typedef __attribute__((ext_vector_type(8))) short short8;
typedef __attribute__((ext_vector_type(4))) float floatx4;

#define I_DIM 256
#define H_DIM 1024
#define B_DIM 64
#define T_DIM 256
#define C_DIM 60
#define NWG   128
#define UPW   8      // hidden units per WG
#define BSTR  68     // pacc row stride (dwords): 16B-aligned, 2-way read aliasing

// LDS layout (bytes)
#define LDS_W_OFF    0        // 2*40*4*16 frags * 16B = 81920
#define LDS_PACC_OFF 81920    // 128 rows * 68 dw * 4B = 34816
#define LDS_BIAS_OFF 116736   // 32*4 = 128
#define LDS_CBUF_OFF 116864   // 512*4 = 2048
#define LDS_HSTG_OFF 118912   // 512*2 = 1024 (16B aligned)
#define LDS_TOTAL    119936

// workspace layout (bytes)
#define WS_XSWZ   0u          // T*B*I bf16 = 8388608
#define WS_HSWZ   8388608u    // 256 slots * 64*1024 bf16 = 33554432 (never reused)
#define WS_CNT    41943040u   // 8 counters, 256B apart = 2048
#define WS_HLAST  41945088u   // 64*1024 f32 = 262144

__device__ __forceinline__ u16 f2bf(float f) {
    u32 u = __float_as_uint(f);
    u32 r = (u + 0x7fffu + ((u >> 16) & 1u)) >> 16;
    return (u16)r;
}
__device__ __forceinline__ float fsig(float x) { return 1.0f / (1.0f + __expf(-x)); }
__device__ __forceinline__ float ftanh(float x) { return 2.0f * fsig(2.0f * x) - 1.0f; }

// ---------------------------------------------------------------------------
// Pre-swizzle inputs [B][T][I] fp32 -> xswz[t] bf16 in MFMA-A-fragment layout:
// 16B unit index (per t): ((mt*8 + s)*4 + q)*16 + m  holds A[b=mt*16+m][k=s*32+q*8 .. +7]
// ---------------------------------------------------------------------------
extern "C" __global__ void prep_x(const float* __restrict__ in, u16* __restrict__ xswz) {
    int o = blockIdx.x * 256 + threadIdx.x;           // octet index, 524288 total
    int m = o & 15, q = (o >> 4) & 3, s = (o >> 6) & 7, mt = (o >> 9) & 3, t = o >> 11;
    int b = mt * 16 + m, k = s * 32 + q * 8;
    const float* src = in + ((size_t)(b * T_DIM + t)) * I_DIM + k;
    float4 v0 = *(const float4*)src;
    float4 v1 = *(const float4*)(src + 4);
    short8 val;
    val[0] = (short)f2bf(v0.x); val[1] = (short)f2bf(v0.y);
    val[2] = (short)f2bf(v0.z); val[3] = (short)f2bf(v0.w);
    val[4] = (short)f2bf(v1.x); val[5] = (short)f2bf(v1.y);
    val[6] = (short)f2bf(v1.z); val[7] = (short)f2bf(v1.w);
    *(short8*)(xswz + (size_t)o * 8) = val;
}

// ---------------------------------------------------------------------------
// Persistent LSTM scan (r8): GATED CACHED BROADCAST over NEVER-REUSED SLOTS.
// h(t) lives in its own 128 KB slot (256 slots total, no ring). A consumer's
// cached h load is therefore always a compulsory L2 miss -> filled from L3,
// where the counter gate guarantees h(t) already resides (producers sc-store,
// wait vmcnt(0), fetch_add; wave0 polls 8 counters before loads issue).
// Stale L2 hits are structurally impossible -> no tags, no retries.
// 16 WGs per XCD share each fetched line in their L2 (L3 traffic ~1 MB/step).
// Upfront 40-deep load MLP retained; wave0 issues x loads before polling.
// ---------------------------------------------------------------------------
extern "C" __global__ void __launch_bounds__(256, 1) lstm_scan(
    const u16* __restrict__ xswz, u16* hswz,
    const float* __restrict__ Wih, const float* __restrict__ Whh,
    const float* __restrict__ bih, const float* __restrict__ bhh,
    int* cnt8, float* hlast)
{
    extern __shared__ char lds[];
    u16*   Wlds   = (u16*)(lds + LDS_W_OFF);
    float* pacc   = (float*)(lds + LDS_PACC_OFF);
    float* bias   = (float*)(lds + LDS_BIAS_OFF);
    float* cbuf   = (float*)(lds + LDS_CBUF_OFF);
    u16*   hstage = (u16*)(lds + LDS_HSTG_OFF);

    const int j    = blockIdx.x;
    const int tid  = threadIdx.x;
    const int lane = tid & 63;
    const int w    = tid >> 6;

    // ---- stage W slice into LDS, bf16, B-swizzled:
    // unit wu = ((nt*40 + sg)*4 + q)*16 + nn  holds W[r(nt,nn)][sg*32+q*8 .. +7]
    for (int i = 0; i < 20; ++i) {
        int wu = tid + i * 256;
        int nn = wu & 15, q = (wu >> 4) & 3, rest = wu >> 6;
        int sg = rest % 40, nt = rest / 40;
        int n = nt * 16 + nn;
        int g = n >> 3, uu = n & 7;
        int r = g * H_DIM + j * UPW + uu;
        int kb = sg * 32 + q * 8;
        const float* src = (kb < I_DIM) ? (Wih + (size_t)r * I_DIM + kb)
                                        : (Whh + (size_t)r * H_DIM + (kb - I_DIM));
        short8 val;
        #pragma unroll
        for (int e = 0; e < 8; ++e) val[e] = (short)f2bf(src[e]);
        *(short8*)(Wlds + (size_t)wu * 8) = val;
    }
    if (tid < 32) {
        int n = tid, g = n >> 3, uu = n & 7;
        int r = g * H_DIM + j * UPW + uu;
        bias[n] = bih[r] + bhh[r];
    }
    for (int i = tid; i < 512; i += 256) cbuf[i] = 0.0f;
    __syncthreads();

    const int m16 = lane & 15, q4 = lane >> 4;

    for (int t = 0; t < T_DIM; ++t) {
        const u16* xbase = xswz + (size_t)t * (B_DIM * I_DIM);
        const u16* hbase = hswz + (size_t)t * (B_DIM * H_DIM);   // fresh slot

        short8 a[10][4];

        // ---- wave0: issue x loads FIRST (independent of h), then poll gate;
        // the x loads drain during the first poll iteration.
        if (w == 0) {
            #pragma unroll
            for (int ss = 0; ss < 8; ++ss)
                #pragma unroll
                for (int mt = 0; mt < 4; ++mt)
                    a[ss][mt] = *(const short8*)(xbase + ((((mt * 8 + ss) * 4) + q4) * 16 + m16) * 8);
            if (t > 0) {
                int target = 16 * t;
                const int* cp = cnt8 + (lane << 6);   // lane*256 bytes
                bool need = lane < 8;
                while (true) {
                    int v = need ? __hip_atomic_load(cp, __ATOMIC_RELAXED,
                                                     __HIP_MEMORY_SCOPE_SYSTEM)
                                 : 0x7fffffff;
                    if (__all(v >= target)) break;
                    __builtin_amdgcn_s_sleep(1);
                }
            }
        }
        __syncthreads();   // (C) gate passed: h(t) is at L3

        // ---- remaining A-frag loads (h part), all upfront (deep MLP)
        if (w == 0) {
            #pragma unroll
            for (int ss = 8; ss < 10; ++ss) {
                const int sgh = ss - 8;
                #pragma unroll
                for (int mt = 0; mt < 4; ++mt)
                    a[ss][mt] = *(const short8*)(hbase + ((((mt * 32 + sgh) * 4) + q4) * 16 + m16) * 8);
            }
        } else {
            #pragma unroll
            for (int ss = 0; ss < 10; ++ss) {
                const int sgh = w * 10 + ss - 8;
                #pragma unroll
                for (int mt = 0; mt < 4; ++mt)
                    a[ss][mt] = *(const short8*)(hbase + ((((mt * 32 + sgh) * 4) + q4) * 16 + m16) * 8);
            }
        }

        // ---- MFMA loop consuming the register array
        floatx4 acc[4][2];
        #pragma unroll
        for (int mt = 0; mt < 4; ++mt)
            #pragma unroll
            for (int nt = 0; nt < 2; ++nt)
                acc[mt][nt] = (floatx4){0.f, 0.f, 0.f, 0.f};

        #pragma unroll
        for (int ss = 0; ss < 10; ++ss) {
            int sg = w * 10 + ss;
            short8 b[2];
            #pragma unroll
            for (int nt = 0; nt < 2; ++nt)
                b[nt] = *(const short8*)(Wlds + ((((nt * 40 + sg) * 4) + q4) * 16 + m16) * 8);
            #pragma unroll
            for (int mt = 0; mt < 4; ++mt)
                #pragma unroll
                for (int nt = 0; nt < 2; ++nt)
                    acc[mt][nt] = __builtin_amdgcn_mfma_f32_16x16x32_bf16(
                        a[ss][mt], b[nt], acc[mt][nt], 0, 0, 0);
        }

        // ---- write K-partials transposed: pacc[(w*32+n)*BSTR + b], b128 stores
        #pragma unroll
        for (int mt = 0; mt < 4; ++mt)
            #pragma unroll
            for (int nt = 0; nt < 2; ++nt)
                *(floatx4*)(pacc + (w * 32 + nt * 16 + m16) * BSTR + mt * 16 + q4 * 4) =
                    acc[mt][nt];
        __syncthreads();   // (A) pacc ready

        // ---- pointwise: reduce partials, gates, c/h update -> hstage
        #pragma unroll
        for (int it = 0; it < 2; ++it) {
            int idx = tid + it * 256;       // (b, uu)
            int b = idx >> 3, uu = idx & 7;
            float s[4];
            #pragma unroll
            for (int g = 0; g < 4; ++g) {
                int n = g * 8 + uu;
                float v = bias[n];
                #pragma unroll
                for (int ww = 0; ww < 4; ++ww) v += pacc[(ww * 32 + n) * BSTR + b];
                s[g] = v;
            }
            float ig = fsig(s[0]), fg = fsig(s[1]), gg = ftanh(s[2]), og = fsig(s[3]);
            float c = fg * cbuf[b * 8 + uu] + ig * gg;
            cbuf[b * 8 + uu] = c;
            float h = og * ftanh(c);
            hstage[b * 8 + uu] = f2bf(h);
            if (t == T_DIM - 1) hlast[b * H_DIM + j * UPW + uu] = h;
        }
        __syncthreads();   // (B) hstage ready; pacc free for next step

        // ---- publish: wave0 sc-stores h(t+1) to its fresh slot, vmcnt(0),
        // fetch_add (gate release)
        if (tid < 64 && t + 1 < T_DIM) {
            int b = tid;
            const u64* hs = (const u64*)hstage;
            u64 lo = hs[b * 2], hi = hs[b * 2 + 1];
            u16* hw = hswz + (size_t)(t + 1) * (B_DIM * H_DIM);
            // unit octet: ((mt*32 + (j>>2))*4 + (j&3))*16 + mm, mt=b>>4, mm=b&15
            u64* dst = (u64*)hw + ((((b >> 4) * 32 + (j >> 2)) * 4 + (j & 3)) * 16 + (b & 15)) * 2;
            __hip_atomic_store(dst,     lo, __ATOMIC_RELAXED, __HIP_MEMORY_SCOPE_SYSTEM);
            __hip_atomic_store(dst + 1, hi, __ATOMIC_RELAXED, __HIP_MEMORY_SCOPE_SYSTEM);
            asm volatile("s_waitcnt vmcnt(0)" ::: "memory");  // h at L3
            if (tid == 0)
                __hip_atomic_fetch_add(cnt8 + ((j >> 4) << 6), 1, __ATOMIC_RELAXED,
                                       __HIP_MEMORY_SCOPE_SYSTEM);
        }
    }
}

// ---------------------------------------------------------------------------
// FC + log_softmax: one wave per batch row. logits[b][c] = h.fc_w[c] + fc_b[c]
// ---------------------------------------------------------------------------
extern "C" __global__ void fc_logsoftmax(const float* __restrict__ hlast,
                                         const float* __restrict__ fcw,
                                         const float* __restrict__ fcb,
                                         float* __restrict__ out)
{
    int b = blockIdx.x, c = threadIdx.x;  // 64 threads, 1 wave
    float acc = 0.0f;
    if (c < C_DIM) {
        const float* wr = fcw + (size_t)c * H_DIM;
        const float* hr = hlast + (size_t)b * H_DIM;
        for (int k = 0; k < H_DIM; k += 4) {
            float4 hv = *(const float4*)(hr + k);
            float4 wv = *(const float4*)(wr + k);
            acc += hv.x * wv.x + hv.y * wv.y + hv.z * wv.z + hv.w * wv.w;
        }
        acc += fcb[c];
    }
    float logit = (c < C_DIM) ? acc : -1e30f;
    float mx = logit;
    #pragma unroll
    for (int off = 32; off; off >>= 1) mx = fmaxf(mx, __shfl_xor(mx, off));
    float e = (c < C_DIM) ? expf(logit - mx) : 0.0f;
    float sum = e;
    #pragma unroll
    for (int off = 32; off; off >>= 1) sum += __shfl_xor(sum, off);
    if (c < C_DIM) out[b * C_DIM + c] = logit - mx - logf(sum);
}

extern "C" void kernel_launch(void* const* d_in, const int* in_sizes, int n_in,
                              void* d_out, int out_size, void* d_ws, size_t ws_size,
                              hipStream_t stream)
{
    const float* inputs = (const float*)d_in[0];
    const float* Wih    = (const float*)d_in[1];
    const float* Whh    = (const float*)d_in[2];
    const float* bih    = (const float*)d_in[3];
    const float* bhh    = (const float*)d_in[4];
    const float* fcw    = (const float*)d_in[5];
    const float* fcb    = (const float*)d_in[6];
    float* out = (float*)d_out;

    char* ws = (char*)d_ws;
    u16*   xswz  = (u16*)(ws + WS_XSWZ);
    u16*   hswz  = (u16*)(ws + WS_HSWZ);
    int*   cnt8  = (int*)(ws + WS_CNT);
    float* hlast = (float*)(ws + WS_HLAST);

    // slot 0 = h_0 = 0; counters = 0. Kernel-boundary release makes these
    // visible to all cached readers.
    hipMemsetAsync(hswz, 0, B_DIM * H_DIM * sizeof(u16), stream);
    hipMemsetAsync(cnt8, 0, 2048, stream);

    prep_x<<<2048, 256, 0, stream>>>(inputs, xswz);

    (void)hipFuncSetAttribute((const void*)lstm_scan,
                              hipFuncAttributeMaxDynamicSharedMemorySize, LDS_TOTAL);
    lstm_scan<<<NWG, 256, LDS_TOTAL, stream>>>(xswz, hswz, Wih, Whh, bih, bhh,
                                               cnt8, hlast);
    fc_logsoftmax<<<B_DIM, 64, 0, stream>>>(hlast, fcw, fcb, out);
}

// Round 9
// 1459.973 us; speedup vs baseline: 2.7611x; 1.0791x over previous
//
#include <hip/hip_runtime.h>
#include <hip/hip_bf16.h>

typedef unsigned short u16;
typedef unsigned int u32;
typedef unsigned long long u64;
typedef __attribute__((ext_vector_type(8))) short short8;
typedef __attribute__((ext_vector_type(4))) float floatx4;

#define I_DIM 256
#define H_DIM 1024
#define B_DIM 64
#define T_DIM 256
#define C_DIM 60
#define NWG   128
#define UPW   8      // hidden units per WG
#define BSTR  68     // pacc row stride (dwords): 16B-aligned, 2-way read aliasing

// LDS layout (bytes)
#define LDS_W_OFF    0        // 2*40*4*16 frags * 16B = 81920
#define LDS_PACC_OFF 81920    // 128 rows * 68 dw * 4B = 34816
#define LDS_BIAS_OFF 116736   // 32*4 = 128
#define LDS_CBUF_OFF 116864   // 512*4 = 2048
#define LDS_HSTG_OFF 118912   // 512*2 = 1024 (16B aligned)
#define LDS_TOTAL    119936

// workspace layout (bytes)
#define WS_XSWZ   0u          // T*B*I bf16 = 8388608
#define WS_HSWZ   8388608u    // 256 slots * 64*1024 bf16 = 33554432 (never reused)
#define WS_CNT    41943040u   // 8 counters, 256B apart = 2048
#define WS_HLAST  41945088u   // 64*1024 f32 = 262144

#define LSBM 0x0001000100010001ull

__device__ __forceinline__ u16 f2bf(float f) {
    u32 u = __float_as_uint(f);
    u32 r = (u + 0x7fffu + ((u >> 16) & 1u)) >> 16;
    return (u16)r;
}
__device__ __forceinline__ float fsig(float x) { return 1.0f / (1.0f + __expf(-x)); }
__device__ __forceinline__ float ftanh(float x) { return 2.0f * fsig(2.0f * x) - 1.0f; }

union hfrag { short8 s; u64 q[2]; };

// ---------------------------------------------------------------------------
// Pre-swizzle inputs [B][T][I] fp32 -> xswz[t] bf16 in MFMA-A-fragment layout:
// 16B unit index (per t): ((mt*8 + s)*4 + q)*16 + m  holds A[b=mt*16+m][k=s*32+q*8 .. +7]
// ---------------------------------------------------------------------------
extern "C" __global__ void prep_x(const float* __restrict__ in, u16* __restrict__ xswz) {
    int o = blockIdx.x * 256 + threadIdx.x;           // octet index, 524288 total
    int m = o & 15, q = (o >> 4) & 3, s = (o >> 6) & 7, mt = (o >> 9) & 3, t = o >> 11;
    int b = mt * 16 + m, k = s * 32 + q * 8;
    const float* src = in + ((size_t)(b * T_DIM + t)) * I_DIM + k;
    float4 v0 = *(const float4*)src;
    float4 v1 = *(const float4*)(src + 4);
    short8 val;
    val[0] = (short)f2bf(v0.x); val[1] = (short)f2bf(v0.y);
    val[2] = (short)f2bf(v0.z); val[3] = (short)f2bf(v0.w);
    val[4] = (short)f2bf(v1.x); val[5] = (short)f2bf(v1.y);
    val[6] = (short)f2bf(v1.z); val[7] = (short)f2bf(v1.w);
    *(short8*)(xswz + (size_t)o * 8) = val;
}

// ---------------------------------------------------------------------------
// Persistent LSTM scan (r9): GATED CACHED BROADCAST, NEVER-REUSED SLOTS,
// ACK-FREE PUBLISH. Producers sc-store h(t+1) (8B agent atomics) and
// fetch_add the group counter IMMEDIATELY (no vmcnt drain) -- counter and
// data race to L3. The gate (wave0 polls 8 counters) is now approximate;
// the race window is closed by in-band stolen-lsb tags (tag=(t%13)+1,
// never 0 = poison), validated per 8B half (tear-safe: producer stores are
// 8B atomics). Stale L2 hits stay structurally impossible (slot per step),
// so the tag-repair path (sc loads) only fires in the store-in-flight
// window -- cold, unlike r7's hot retry storm.
// ---------------------------------------------------------------------------
extern "C" __global__ void __launch_bounds__(256, 1) lstm_scan(
    const u16* __restrict__ xswz, u16* hswz,
    const float* __restrict__ Wih, const float* __restrict__ Whh,
    const float* __restrict__ bih, const float* __restrict__ bhh,
    int* cnt8, float* hlast)
{
    extern __shared__ char lds[];
    u16*   Wlds   = (u16*)(lds + LDS_W_OFF);
    float* pacc   = (float*)(lds + LDS_PACC_OFF);
    float* bias   = (float*)(lds + LDS_BIAS_OFF);
    float* cbuf   = (float*)(lds + LDS_CBUF_OFF);
    u16*   hstage = (u16*)(lds + LDS_HSTG_OFF);

    const int j    = blockIdx.x;
    const int tid  = threadIdx.x;
    const int lane = tid & 63;
    const int w    = tid >> 6;

    // ---- stage W slice into LDS, bf16, B-swizzled:
    // unit wu = ((nt*40 + sg)*4 + q)*16 + nn  holds W[r(nt,nn)][sg*32+q*8 .. +7]
    for (int i = 0; i < 20; ++i) {
        int wu = tid + i * 256;
        int nn = wu & 15, q = (wu >> 4) & 3, rest = wu >> 6;
        int sg = rest % 40, nt = rest / 40;
        int n = nt * 16 + nn;
        int g = n >> 3, uu = n & 7;
        int r = g * H_DIM + j * UPW + uu;
        int kb = sg * 32 + q * 8;
        const float* src = (kb < I_DIM) ? (Wih + (size_t)r * I_DIM + kb)
                                        : (Whh + (size_t)r * H_DIM + (kb - I_DIM));
        short8 val;
        #pragma unroll
        for (int e = 0; e < 8; ++e) val[e] = (short)f2bf(src[e]);
        *(short8*)(Wlds + (size_t)wu * 8) = val;
    }
    if (tid < 32) {
        int n = tid, g = n >> 3, uu = n & 7;
        int r = g * H_DIM + j * UPW + uu;
        bias[n] = bih[r] + bhh[r];
    }
    for (int i = tid; i < 512; i += 256) cbuf[i] = 0.0f;
    __syncthreads();

    const int m16 = lane & 15, q4 = lane >> 4;

    for (int t = 0; t < T_DIM; ++t) {
        const u16* xbase = xswz + (size_t)t * (B_DIM * I_DIM);
        const u16* hbase = hswz + (size_t)t * (B_DIM * H_DIM);   // fresh slot
        const int  En    = (t % 13) + 1;          // tag nibble, never 0
        const u64  Eq    = (u64)(En & 1) | ((u64)((En >> 1) & 1) << 16)
                         | ((u64)((En >> 2) & 1) << 32) | ((u64)((En >> 3) & 1) << 48);

        hfrag a[10][4];

        // ---- wave0: issue x loads FIRST (independent of h), then poll gate;
        // the x loads drain during the first poll iteration.
        if (w == 0) {
            #pragma unroll
            for (int ss = 0; ss < 8; ++ss)
                #pragma unroll
                for (int mt = 0; mt < 4; ++mt)
                    a[ss][mt].s = *(const short8*)(xbase + ((((mt * 8 + ss) * 4) + q4) * 16 + m16) * 8);
            if (t > 0) {
                int target = 16 * t;
                const int* cp = cnt8 + (lane << 6);   // lane*256 bytes
                bool need = lane < 8;
                while (true) {
                    int v = need ? __hip_atomic_load(cp, __ATOMIC_RELAXED,
                                                     __HIP_MEMORY_SCOPE_AGENT)
                                 : 0x7fffffff;
                    if (__all(v >= target)) break;
                    __builtin_amdgcn_s_sleep(1);
                }
            }
        }
        __syncthreads();   // (C) gate passed: h(t) at (or racing to) L3

        // ---- h-part A-frag loads, cached, all upfront (deep MLP)
        if (w == 0) {
            #pragma unroll
            for (int ss = 8; ss < 10; ++ss) {
                const int sgh = ss - 8;
                #pragma unroll
                for (int mt = 0; mt < 4; ++mt)
                    a[ss][mt].s = *(const short8*)(hbase + ((((mt * 32 + sgh) * 4) + q4) * 16 + m16) * 8);
            }
        } else {
            #pragma unroll
            for (int ss = 0; ss < 10; ++ss) {
                const int sgh = w * 10 + ss - 8;
                #pragma unroll
                for (int mt = 0; mt < 4; ++mt)
                    a[ss][mt].s = *(const short8*)(hbase + ((((mt * 32 + sgh) * 4) + q4) * 16 + m16) * 8);
            }
        }

        // ---- validate tags (t>0); in-flight-window misses repaired via sc
        if (t > 0) {
            u64 m = 0;
            #pragma unroll
            for (int ss = 0; ss < 10; ++ss) {
                if (w * 10 + ss >= 8) {
                    #pragma unroll
                    for (int mt = 0; mt < 4; ++mt)
                        if ((((a[ss][mt].q[0] ^ Eq) | (a[ss][mt].q[1] ^ Eq)) & LSBM) != 0)
                            m |= 1ull << (ss * 4 + mt);
                }
            }
            while (__any(m != 0)) {
                #pragma unroll
                for (int ss = 0; ss < 10; ++ss) {
                    const int sg = w * 10 + ss;
                    if (sg >= 8) {
                        const int sgh = sg - 8;
                        #pragma unroll
                        for (int mt = 0; mt < 4; ++mt)
                            if ((m >> (ss * 4 + mt)) & 1) {
                                const u64* p = (const u64*)hbase
                                    + ((((mt * 32 + sgh) * 4) + q4) * 16 + m16) * 2;
                                a[ss][mt].q[0] = __hip_atomic_load(p,     __ATOMIC_RELAXED, __HIP_MEMORY_SCOPE_AGENT);
                                a[ss][mt].q[1] = __hip_atomic_load(p + 1, __ATOMIC_RELAXED, __HIP_MEMORY_SCOPE_AGENT);
                            }
                    }
                }
                #pragma unroll
                for (int ss = 0; ss < 10; ++ss) {
                    if (w * 10 + ss >= 8) {
                        #pragma unroll
                        for (int mt = 0; mt < 4; ++mt)
                            if (((m >> (ss * 4 + mt)) & 1) &&
                                ((((a[ss][mt].q[0] ^ Eq) | (a[ss][mt].q[1] ^ Eq)) & LSBM) == 0))
                                m &= ~(1ull << (ss * 4 + mt));
                    }
                }
            }
        }

        // ---- MFMA loop consuming the register array
        floatx4 acc[4][2];
        #pragma unroll
        for (int mt = 0; mt < 4; ++mt)
            #pragma unroll
            for (int nt = 0; nt < 2; ++nt)
                acc[mt][nt] = (floatx4){0.f, 0.f, 0.f, 0.f};

        #pragma unroll
        for (int ss = 0; ss < 10; ++ss) {
            int sg = w * 10 + ss;
            short8 b[2];
            #pragma unroll
            for (int nt = 0; nt < 2; ++nt)
                b[nt] = *(const short8*)(Wlds + ((((nt * 40 + sg) * 4) + q4) * 16 + m16) * 8);
            #pragma unroll
            for (int mt = 0; mt < 4; ++mt)
                #pragma unroll
                for (int nt = 0; nt < 2; ++nt)
                    acc[mt][nt] = __builtin_amdgcn_mfma_f32_16x16x32_bf16(
                        a[ss][mt].s, b[nt], acc[mt][nt], 0, 0, 0);
        }

        // ---- write K-partials transposed: pacc[(w*32+n)*BSTR + b], b128 stores
        #pragma unroll
        for (int mt = 0; mt < 4; ++mt)
            #pragma unroll
            for (int nt = 0; nt < 2; ++nt)
                *(floatx4*)(pacc + (w * 32 + nt * 16 + m16) * BSTR + mt * 16 + q4 * 4) =
                    acc[mt][nt];
        __syncthreads();   // (A) pacc ready

        // ---- pointwise: reduce partials, gates, c/h update -> hstage (tagged)
        const int Ep = ((t + 1) % 13) + 1;
        #pragma unroll
        for (int it = 0; it < 2; ++it) {
            int idx = tid + it * 256;       // (b, uu)
            int b = idx >> 3, uu = idx & 7;
            float s[4];
            #pragma unroll
            for (int g = 0; g < 4; ++g) {
                int n = g * 8 + uu;
                float v = bias[n];
                #pragma unroll
                for (int ww = 0; ww < 4; ++ww) v += pacc[(ww * 32 + n) * BSTR + b];
                s[g] = v;
            }
            float ig = fsig(s[0]), fg = fsig(s[1]), gg = ftanh(s[2]), og = fsig(s[3]);
            float c = fg * cbuf[b * 8 + uu] + ig * gg;
            cbuf[b * 8 + uu] = c;
            float h = og * ftanh(c);
            // steal lsb: tag bit (uu&3) of next step's nibble
            hstage[b * 8 + uu] = (u16)((f2bf(h) & 0xFFFEu) | ((Ep >> (uu & 3)) & 1));
            if (t == T_DIM - 1) hlast[b * H_DIM + j * UPW + uu] = h;
        }
        __syncthreads();   // (B) hstage ready; pacc free for next step

        // ---- publish: wave0 sc-stores h(t+1), then fetch_add IMMEDIATELY
        // (no vmcnt drain -- tags close the race window)
        if (tid < 64 && t + 1 < T_DIM) {
            int b = tid;
            const u64* hs = (const u64*)hstage;
            u64 lo = hs[b * 2], hi = hs[b * 2 + 1];
            u16* hw = hswz + (size_t)(t + 1) * (B_DIM * H_DIM);
            // unit octet: ((mt*32 + (j>>2))*4 + (j&3))*16 + mm, mt=b>>4, mm=b&15
            u64* dst = (u64*)hw + ((((b >> 4) * 32 + (j >> 2)) * 4 + (j & 3)) * 16 + (b & 15)) * 2;
            __hip_atomic_store(dst,     lo, __ATOMIC_RELAXED, __HIP_MEMORY_SCOPE_AGENT);
            __hip_atomic_store(dst + 1, hi, __ATOMIC_RELAXED, __HIP_MEMORY_SCOPE_AGENT);
            if (tid == 0)
                __hip_atomic_fetch_add(cnt8 + ((j >> 4) << 6), 1, __ATOMIC_RELAXED,
                                       __HIP_MEMORY_SCOPE_AGENT);
        }
    }
}

// ---------------------------------------------------------------------------
// FC + log_softmax: one wave per batch row. logits[b][c] = h.fc_w[c] + fc_b[c]
// ---------------------------------------------------------------------------
extern "C" __global__ void fc_logsoftmax(const float* __restrict__ hlast,
                                         const float* __restrict__ fcw,
                                         const float* __restrict__ fcb,
                                         float* __restrict__ out)
{
    int b = blockIdx.x, c = threadIdx.x;  // 64 threads, 1 wave
    float acc = 0.0f;
    if (c < C_DIM) {
        const float* wr = fcw + (size_t)c * H_DIM;
        const float* hr = hlast + (size_t)b * H_DIM;
        for (int k = 0; k < H_DIM; k += 4) {
            float4 hv = *(const float4*)(hr + k);
            float4 wv = *(const float4*)(wr + k);
            acc += hv.x * wv.x + hv.y * wv.y + hv.z * wv.z + hv.w * wv.w;
        }
        acc += fcb[c];
    }
    float logit = (c < C_DIM) ? acc : -1e30f;
    float mx = logit;
    #pragma unroll
    for (int off = 32; off; off >>= 1) mx = fmaxf(mx, __shfl_xor(mx, off));
    float e = (c < C_DIM) ? expf(logit - mx) : 0.0f;
    float sum = e;
    #pragma unroll
    for (int off = 32; off; off >>= 1) sum += __shfl_xor(sum, off);
    if (c < C_DIM) out[b * C_DIM + c] = logit - mx - logf(sum);
}

extern "C" void kernel_launch(void* const* d_in, const int* in_sizes, int n_in,
                              void* d_out, int out_size, void* d_ws, size_t ws_size,
                              hipStream_t stream)
{
    const float* inputs = (const float*)d_in[0];
    const float* Wih    = (const float*)d_in[1];
    const float* Whh    = (const float*)d_in[2];
    const float* bih    = (const float*)d_in[3];
    const float* bhh    = (const float*)d_in[4];
    const float* fcw    = (const float*)d_in[5];
    const float* fcb    = (const float*)d_in[6];
    float* out = (float*)d_out;

    char* ws = (char*)d_ws;
    u16*   xswz  = (u16*)(ws + WS_XSWZ);
    u16*   hswz  = (u16*)(ws + WS_HSWZ);
    int*   cnt8  = (int*)(ws + WS_CNT);
    float* hlast = (float*)(ws + WS_HLAST);

    // slot 0 = h_0 = 0 (t=0 skips tag check); counters = 0. Slots t>=1 keep
    // harness poison 0xAA whose tag nibble is 0 -> never validates early.
    hipMemsetAsync(hswz, 0, B_DIM * H_DIM * sizeof(u16), stream);
    hipMemsetAsync(cnt8, 0, 2048, stream);

    prep_x<<<2048, 256, 0, stream>>>(inputs, xswz);

    (void)hipFuncSetAttribute((const void*)lstm_scan,
                              hipFuncAttributeMaxDynamicSharedMemorySize, LDS_TOTAL);
    lstm_scan<<<NWG, 256, LDS_TOTAL, stream>>>(xswz, hswz, Wih, Whh, bih, bhh,
                                               cnt8, hlast);
    fc_logsoftmax<<<B_DIM, 64, 0, stream>>>(hlast, fcw, fcb, out);
}